// Round 15
// baseline (8661.832 us; speedup 1.0000x reference)
//
#include <hip/hip_runtime.h>
#include <hip/hip_bf16.h>
#include <math.h>

#define TSEQ 4096
#define EMBD 1024
#define HH   512
#define NTAGS 5
#define NGATE 2048
#define NEGV (-10000.0f)
#define START_TAG 3
#define STOP_TAG 4
#define LSTM_WGS 64
#define PROJ_WGS 1024
#define VIT_BLOCK (LSTM_WGS + PROJ_WGS)

typedef unsigned long long u64;
typedef unsigned int u32;

__device__ __forceinline__ float sigm(float x){ return 1.0f/(1.0f+expf(-x)); }

__device__ __forceinline__ u64 pack_pair(float h, u32 tag){
  return ((u64)tag << 32) | (u64)__float_as_uint(h);
}

// ---------------- init: prime h pair buffers + zero control counters ----------
__global__ void k_init(const float* __restrict__ h0, u64* __restrict__ hx2,
                       int* __restrict__ rdy){
  int tid = threadIdx.x;
  if (tid < 1024){
    int dir = tid >> 9, u = tid & 511;
    hx2[(dir*2 + 0)*HH + u] = pack_pair(h0[dir*HH + u], 0u);
    hx2[(dir*2 + 1)*HH + u] = pack_pair(0.f, 0xFFFFFFFFu);
  }
  if (tid < 96) rdy[tid] = 0;  // [0..63] tile-ready, [65] lstm-done, [66] feats-done
}

// ------- fully fused: BiLSTM + inproj GEMM + feats epilogue + viterbi ----------
// blocks 0..63: lstm (+feats epilogue). 64..1087: inproj GEMM. 1088: viterbi.
// R15: viterbi forward rewritten in 4-step blocks with NAMED registers — the
// R14 version's fA[16]/fE[16] (80+ floats vs VGPR_Count=68) was spilled to
// scratch by the allocator, making the hot chain memory-bound (~1.5ms).
__global__ __launch_bounds__(512, 2) void k_fused(
    const int* __restrict__ sent, const float* __restrict__ emb,
    const float* __restrict__ Wif, const float* __restrict__ bf,
    const float* __restrict__ Wib, const float* __restrict__ bb,
    const float* __restrict__ Whf, const float* __restrict__ Whb,
    const float* __restrict__ c0, const float* __restrict__ Wout,
    const float* __restrict__ bout, const float* __restrict__ trans,
    float* __restrict__ A, float* __restrict__ hseq, float* __restrict__ feats,
    int* __restrict__ bpw, float* __restrict__ out,
    u64* __restrict__ hx2, int* __restrict__ rdy){
  __shared__ __align__(16) char smem[17408];
  const int tid = threadIdx.x;

  if (blockIdx.x == VIT_BLOCK){
    // ================= viterbi role (1 wave) =================
    if (tid >= 64) return;
    const int lane = tid;
    while (__hip_atomic_load(&rdy[66], __ATOMIC_ACQUIRE, __HIP_MEMORY_SCOPE_AGENT) < LSTM_WGS)
      __builtin_amdgcn_s_sleep(8);
    // T in named scalars (25 regs)
    const float T00=trans[0],  T01=trans[1],  T02=trans[2],  T03=trans[3],  T04=trans[4];
    const float T10=trans[5],  T11=trans[6],  T12=trans[7],  T13=trans[8],  T14=trans[9];
    const float T20=trans[10], T21=trans[11], T22=trans[12], T23=trans[13], T24=trans[14];
    const float T30=trans[15], T31=trans[16], T32=trans[17], T33=trans[18], T34=trans[19];
    const float T40=trans[20], T41=trans[21], T42=trans[22], T43=trans[23], T44=trans[24];
    float fv0 = NEGV, fv1 = NEGV, fv2 = NEGV, fv3 = 0.f, fv4 = NEGV; // START=3

#define VROW(Ta,Tb,Tc,Td,Te, OUTM, OUTI)                                   \
    {                                                                       \
      const float n0 = fv0 + Ta, n1 = fv1 + Tb, n2 = fv2 + Tc,              \
                  n3 = fv3 + Td, n4 = fv4 + Te;                             \
      OUTM = fmaxf(fmaxf(fmaxf(n0, n1), fmaxf(n2, n3)), n4);                \
      OUTI = (n0 == OUTM) ? 0 : ((n1 == OUTM) ? 1 : ((n2 == OUTM) ? 2 :     \
             ((n3 == OUTM) ? 3 : 4)));                                      \
    }
#define VSTEP(fa, fe, tcur)                                                 \
    {                                                                       \
      float m0,m1,m2,m3,m4; int i0,i1,i2,i3,i4;                             \
      VROW(T00,T01,T02,T03,T04, m0,i0)                                      \
      VROW(T10,T11,T12,T13,T14, m1,i1)                                      \
      VROW(T20,T21,T22,T23,T24, m2,i2)                                      \
      VROW(T30,T31,T32,T33,T34, m3,i3)                                      \
      VROW(T40,T41,T42,T43,T44, m4,i4)                                      \
      const int pack = i0 | (i1<<4) | (i2<<8) | (i3<<12) | (i4<<16);        \
      fv0 = m0 + (fa).x; fv1 = m1 + (fa).y; fv2 = m2 + (fa).z;              \
      fv3 = m3 + (fa).w; fv4 = m4 + (fe);                                   \
      if (lane == 0) bpw[tcur] = pack;                                      \
    }

    for (int t0 = 0; t0 < TSEQ; t0 += 4){
      const float4 a0 = *(const float4*)(feats + (t0+0)*8);
      const float  e0 = feats[(t0+0)*8 + 4];
      const float4 a1 = *(const float4*)(feats + (t0+1)*8);
      const float  e1 = feats[(t0+1)*8 + 4];
      const float4 a2 = *(const float4*)(feats + (t0+2)*8);
      const float  e2 = feats[(t0+2)*8 + 4];
      const float4 a3 = *(const float4*)(feats + (t0+3)*8);
      const float  e3 = feats[(t0+3)*8 + 4];
      VSTEP(a0, e0, t0+0)
      VSTEP(a1, e1, t0+1)
      VSTEP(a2, e2, t0+2)
      VSTEP(a3, e3, t0+3)
    }
    {
      const float n0 = fv0 + T40, n1 = fv1 + T41, n2 = fv2 + T42,
                  n3 = fv3 + T43, n4 = fv4 + T44;   // STOP row
      const float m  = fmaxf(fmaxf(fmaxf(n0, n1), fmaxf(n2, n3)), n4);
      const int btag = (n0 == m) ? 0 : ((n1 == m) ? 1 : ((n2 == m) ? 2 : ((n3 == m) ? 3 : 4)));
      if (lane == 0){ out[0] = m; out[TSEQ] = (float)btag; }
      int tag = btag;
      for (int tb = TSEQ - 1; tb >= 1; tb -= 16){
        int w[16];
        #pragma unroll
        for (int i = 0; i < 16; i++){
          const int t = tb - i;
          w[i] = (t >= 1) ? bpw[t] : 0;
        }
        #pragma unroll
        for (int i = 0; i < 16; i++){
          const int t = tb - i;
          if (t >= 1){
            const int prev = (w[i] >> (tag*4)) & 15;
            if (lane == 0) out[t] = (float)prev;
            tag = prev;
          }
        }
      }
    }
    return;
  }

  if (blockIdx.x >= LSTM_WGS){
    // ================= inproj GEMM role =================
    float (*As)[132] = (float(*)[132])smem;              // 16 x 132
    float (*Bs)[132] = (float(*)[132])(smem + 8448);     // 16 x 132
    int* srow        = (int*)(smem + 16896);             // 128
    const int p   = blockIdx.x - LSTM_WGS;               // 0..1023
    const int ti  = p >> 5;                              // 0..31
    const int yy  = p & 31;                              // 0..31
    const int dir = yy >> 4;
    const int t_tile = dir ? (31 - ti) : ti;             // two-ended production
    const int t0  = t_tile * 128;
    const int n0  = (yy & 15) * 128;
    const float* __restrict__ W    = dir ? Wib : Wif;
    const float* __restrict__ bias = dir ? bb : bf;
    if (tid < 128) srow[tid] = sent[t0 + tid];
    __syncthreads();
    const int lr = tid >> 2;            // 0..127
    const int kq = (tid & 3) * 4;
    const float* ea = emb + (size_t)srow[lr]   * EMBD + kq;
    const float* wb = W + (size_t)(n0 + lr)    * EMBD + kq;
    const int tx = tid & 15, ty = tid >> 4;   // ty 0..31
    float acc[4][8];
    #pragma unroll
    for (int i = 0; i < 4; i++)
      #pragma unroll
      for (int j = 0; j < 8; j++) acc[i][j] = 0.f;

    for (int k0 = 0; k0 < EMBD; k0 += 16){
      float4 va = *(const float4*)(ea + k0);
      float4 vb = *(const float4*)(wb + k0);
      As[kq+0][lr] = va.x; As[kq+1][lr] = va.y; As[kq+2][lr] = va.z; As[kq+3][lr] = va.w;
      Bs[kq+0][lr] = vb.x; Bs[kq+1][lr] = vb.y; Bs[kq+2][lr] = vb.z; Bs[kq+3][lr] = vb.w;
      __syncthreads();
      #pragma unroll
      for (int k = 0; k < 16; k++){
        float a[4], b[8];
        *(float4*)&a[0] = *(const float4*)&As[k][ty*4];
        #pragma unroll
        for (int j = 0; j < 8; j++) b[j] = Bs[k][tx + 16*j];
        #pragma unroll
        for (int i = 0; i < 4; i++)
          #pragma unroll
          for (int j = 0; j < 8; j++)
            acc[i][j] = fmaf(a[i], b[j], acc[i][j]);
      }
      __syncthreads();
    }
    float bj[8];
    #pragma unroll
    for (int j = 0; j < 8; j++) bj[j] = bias[n0 + tx + 16*j];
    float* Abase = A + (size_t)dir * TSEQ * NGATE;
    #pragma unroll
    for (int i = 0; i < 4; i++){
      float* dst = Abase + (size_t)(t0 + ty*4 + i) * NGATE + n0 + tx;
      #pragma unroll
      for (int j = 0; j < 8; j++) dst[16*j] = acc[i][j] + bj[j];
    }
    __syncthreads();   // drains every wave's stores (HIP barrier semantics)
    if (tid == 0)
      __hip_atomic_fetch_add(&rdy[dir*32 + t_tile], 1,
                             __ATOMIC_RELEASE, __HIP_MEMORY_SCOPE_AGENT);
    return;
  }

  // ================= persistent lstm role =================
  float* hlbuf = (float*)smem;                 // [2][8*68]
  const int bid  = blockIdx.x;
  const int dir  = bid >> 5;
  const int wg   = bid & 31;
  const int lane = tid & 63;
  const int wv   = tid >> 6;        // wave 0..7 = slice index
  const int ul   = tid >> 5;        // unit local 0..15
  const int g    = (tid >> 3) & 3;  // gate i,f,g,o
  const int q    = tid & 7;         // column octant
  const int unit = wg*16 + ul;
  const float* __restrict__ Wh = dir ? Whb : Whf;

  float wreg[64];                   // Wh[g*512+unit][q*64 .. q*64+63]
  {
    const float* wr = Wh + (size_t)(g*HH + unit)*HH + q*64;
    #pragma unroll
    for (int j4 = 0; j4 < 16; j4++){
      float4 vv;
      // volatile load: result cannot be rematerialized -> stays in VGPRs
      asm volatile("global_load_dwordx4 %0, %1, off\n\t"
                   "s_waitcnt vmcnt(0)"
                   : "=v"(vv) : "v"(wr + 4*j4) : "memory");
      wreg[4*j4+0]=vv.x; wreg[4*j4+1]=vv.y; wreg[4*j4+2]=vv.z; wreg[4*j4+3]=vv.w;
    }
  }
  float creg = 0.f;
  if (g == 0 && q == 0) creg = c0[dir*HH + unit];

  u64* mb = hx2 + (size_t)dir*2*HH;
  const float* __restrict__ Ab = A + (size_t)dir*TSEQ*NGATE;
  const int sidx = (wv << 6) + lane;            // this wave's pair index

  // tile-gate + A prefetch for s=0
  int cur_tile = (dir ? (TSEQ - 1) : 0) >> 7;
  {
    const int* rf = rdy + dir*32 + cur_tile;
    while (__hip_atomic_load(rf, __ATOMIC_ACQUIRE, __HIP_MEMORY_SCOPE_AGENT) < 16)
      __builtin_amdgcn_s_sleep(2);
  }
  float av = 0.f;
  if (q == 0) av = Ab[(size_t)(dir ? (TSEQ - 1) : 0)*NGATE + g*HH + unit];

  for (int s = 0; s < TSEQ; s++){
    const int t = dir ? (TSEQ - 1 - s) : s;

    {  // every wave: poll own 64-pair slice (1 load/lane/round, masked reload)
      u64* src = mb + (size_t)(s & 1)*HH;
      const u32 su = (u32)s;
      u64 v = __hip_atomic_load(&src[sidx], __ATOMIC_RELAXED, __HIP_MEMORY_SCOPE_AGENT);
      while (!__all((u32)(v >> 32) == su)){
        if ((u32)(v >> 32) != su)
          v = __hip_atomic_load(&src[sidx], __ATOMIC_RELAXED, __HIP_MEMORY_SCOPE_AGENT);
      }
      hlbuf[(s & 1)*(8*68) + wv*68 + lane] = __uint_as_float((u32)v);
    }
    __syncthreads();

    // prefetch A for step s+1 (resolves under the matvec, off the poll path)
    float av_next = 0.f;
    if (s + 1 < TSEQ){
      const int t1 = dir ? (TSEQ - 2 - s) : (s + 1);
      const int tile1 = t1 >> 7;
      if (tile1 != cur_tile){
        cur_tile = tile1;
        const int* rf = rdy + dir*32 + tile1;
        while (__hip_atomic_load(rf, __ATOMIC_ACQUIRE, __HIP_MEMORY_SCOPE_AGENT) < 16)
          __builtin_amdgcn_s_sleep(2);
      }
      if (q == 0) av_next = Ab[(size_t)t1*NGATE + g*HH + unit];
    }

    // matvec: 64 FMAs from LDS chunk q (weights register-resident)
    const float* hq = hlbuf + (s & 1)*(8*68) + q*68;
    float p0 = 0.f, p1 = 0.f, p2 = 0.f, p3 = 0.f;
    #pragma unroll
    for (int j4 = 0; j4 < 16; j4++){
      float4 h4 = *(const float4*)(hq + 4*j4);
      p0 = fmaf(wreg[4*j4+0], h4.x, p0);
      p1 = fmaf(wreg[4*j4+1], h4.y, p1);
      p2 = fmaf(wreg[4*j4+2], h4.z, p2);
      p3 = fmaf(wreg[4*j4+3], h4.w, p3);
    }
    float acc = ((p0 + p1) + (p2 + p3)) + av;
    acc += __shfl_xor(acc, 1);
    acc += __shfl_xor(acc, 2);
    acc += __shfl_xor(acc, 4);
    // parallel nonlinearity: one transcendental per gate lane
    const float act = (g == 2) ? tanhf(acc) : sigm(acc);
    const float f_ = __shfl_down(act, 8);
    const float g_ = __shfl_down(act, 16);
    const float o_ = __shfl_down(act, 24);
    if (g == 0 && q == 0){
      const float c2 = f_*creg + act*g_;
      const float h2 = o_*tanhf(c2);
      creg = c2;
      // publish FIRST (critical path), bookkeeping store after
      __hip_atomic_store(&mb[(size_t)((s + 1) & 1)*HH + unit], pack_pair(h2, (u32)(s + 1)),
                         __ATOMIC_RELAXED, __HIP_MEMORY_SCOPE_AGENT);
      hseq[((size_t)dir*TSEQ + t)*HH + unit] = h2;
    }
    av = av_next;
  }

  // ---------- feats epilogue: wait for all 64 lstm blocks, then 64 t-rows ------
  __syncthreads();   // all this block's hseq stores issued
  if (tid == 0)
    __hip_atomic_fetch_add(&rdy[65], 1, __ATOMIC_RELEASE, __HIP_MEMORY_SCOPE_AGENT);
  while (__hip_atomic_load(&rdy[65], __ATOMIC_ACQUIRE, __HIP_MEMORY_SCOPE_AGENT) < LSTM_WGS)
    __builtin_amdgcn_s_sleep(2);
  {
    const int wvi = tid >> 6;    // wave 0..7, each does 8 t values
    #pragma unroll
    for (int k = 0; k < 8; k++){
      const int t = bid*64 + wvi*8 + k;
      const float* hf = hseq + (size_t)t*HH;
      const float* hb = hseq + (size_t)(TSEQ + t)*HH;
      float x[16];
      #pragma unroll
      for (int j = 0; j < 8; j++) x[j]     = hf[lane + 64*j];
      #pragma unroll
      for (int j = 0; j < 8; j++) x[8 + j] = hb[lane + 64*j];
      #pragma unroll
      for (int n = 0; n < NTAGS; n++){
        const float* wr = Wout + (size_t)n*(2*HH);
        float p = 0.f;
        #pragma unroll
        for (int j = 0; j < 8; j++) p = fmaf(x[j],     wr[lane + 64*j],      p);
        #pragma unroll
        for (int j = 0; j < 8; j++) p = fmaf(x[8 + j], wr[HH + lane + 64*j], p);
        #pragma unroll
        for (int d = 1; d < 64; d <<= 1) p += __shfl_xor(p, d);
        if (lane == 0) feats[t*8 + n] = p + bout[n];
      }
    }
  }
  __syncthreads();   // all this block's feats stores issued
  if (tid == 0)
    __hip_atomic_fetch_add(&rdy[66], 1, __ATOMIC_RELEASE, __HIP_MEMORY_SCOPE_AGENT);
}

extern "C" void kernel_launch(void* const* d_in, const int* in_sizes, int n_in,
                              void* d_out, int out_size, void* d_ws, size_t ws_size,
                              hipStream_t stream) {
  const int*   sent = (const int*)  d_in[0];
  const float* emb  = (const float*)d_in[1];
  const float* Wihf = (const float*)d_in[2];
  const float* Whhf = (const float*)d_in[3];
  const float* bf_  = (const float*)d_in[4];
  const float* Wihb = (const float*)d_in[5];
  const float* Whhb = (const float*)d_in[6];
  const float* bb_  = (const float*)d_in[7];
  const float* Wout = (const float*)d_in[8];
  const float* bout = (const float*)d_in[9];
  const float* trans= (const float*)d_in[10];
  const float* h0   = (const float*)d_in[11];
  const float* c0   = (const float*)d_in[12];
  float* out = (float*)d_out;

  float* ws   = (float*)d_ws;
  float* A    = ws;                                  // [2][T][2048]
  float* hseq = A    + (size_t)2*TSEQ*NGATE;         // [2][T][512]
  u64*   hx2  = (u64*)(hseq + (size_t)2*TSEQ*HH);    // [2][2][512] (tag,val) pairs
  float* fe   = (float*)(hx2 + 2048);                // [T][8]
  int*   bpw  = (int*)(fe + (size_t)TSEQ*8);         // [T] packed nibbles
  int*   rdy  = bpw + TSEQ;                          // [64] tile-ready + [65][66]
  (void)ws_size;

  k_init<<<1, 1024, 0, stream>>>(h0, hx2, rdy);
  k_fused<<<VIT_BLOCK + 1, 512, 0, stream>>>(
      sent, emb, Wihf, bf_, Wihb, bb_, Whhf, Whhb, c0, Wout, bout, trans,
      A, hseq, fe, bpw, out, hx2, rdy);
}

// Round 16
// 8381.299 us; speedup vs baseline: 1.0335x; 1.0335x over previous
//
#include <hip/hip_runtime.h>
#include <hip/hip_bf16.h>
#include <math.h>

#define TSEQ 4096
#define EMBD 1024
#define HH   512
#define NTAGS 5
#define NGATE 2048
#define NEGV (-10000.0f)
#define START_TAG 3
#define STOP_TAG 4
#define LSTM_WGS 64
#define PROJ_WGS 1024
#define VIT_BLOCK (LSTM_WGS + PROJ_WGS)

typedef unsigned long long u64;
typedef unsigned int u32;

__device__ __forceinline__ float sigm(float x){ return 1.0f/(1.0f+expf(-x)); }

__device__ __forceinline__ u64 pack_pair(float h, u32 tag){
  return ((u64)tag << 32) | (u64)__float_as_uint(h);
}

// ---------------- init: prime h pair buffers + zero control counters ----------
__global__ void k_init(const float* __restrict__ h0, u64* __restrict__ hx2,
                       int* __restrict__ rdy){
  int tid = threadIdx.x;
  if (tid < 1024){
    int dir = tid >> 9, u = tid & 511;
    hx2[(dir*2 + 0)*HH + u] = pack_pair(h0[dir*HH + u], 0u);
    hx2[(dir*2 + 1)*HH + u] = pack_pair(0.f, 0xFFFFFFFFu);
  }
  if (tid < 96) rdy[tid] = 0;  // [0..63] tile-ready, [65] lstm-done, [66] feats-done
}

// ------- fully fused: BiLSTM + inproj GEMM + feats epilogue + viterbi ----------
// blocks 0..63: lstm (+feats epilogue). 64..1087: inproj GEMM. 1088: viterbi.
// R16: viterbi reads feats via bulk-parallel LDS staging (8 chunks x 512 steps,
// 64-lane coalesced fetch) — R14/R15's ~1.45ms was 1024 SERIALIZED cross-XCD
// read round trips (uniform loads + vmcnt(0) in the dependent chain); staging
// converts them to ~8 throughput-bound parallel fetches.
__global__ __launch_bounds__(512, 2) void k_fused(
    const int* __restrict__ sent, const float* __restrict__ emb,
    const float* __restrict__ Wif, const float* __restrict__ bf,
    const float* __restrict__ Wib, const float* __restrict__ bb,
    const float* __restrict__ Whf, const float* __restrict__ Whb,
    const float* __restrict__ c0, const float* __restrict__ Wout,
    const float* __restrict__ bout, const float* __restrict__ trans,
    float* __restrict__ A, float* __restrict__ hseq, float* __restrict__ feats,
    int* __restrict__ bpw, float* __restrict__ out,
    u64* __restrict__ hx2, int* __restrict__ rdy){
  __shared__ __align__(16) char smem[17408];
  const int tid = threadIdx.x;

  if (blockIdx.x == VIT_BLOCK){
    // ================= viterbi role (1 wave) =================
    if (tid >= 64) return;
    const int lane = tid;
    while (__hip_atomic_load(&rdy[66], __ATOMIC_ACQUIRE, __HIP_MEMORY_SCOPE_AGENT) < LSTM_WGS)
      __builtin_amdgcn_s_sleep(8);
    float*  sf  = (float*)smem;        // staged feats chunk: 512 steps x 8 = 16KB
    float4* sf4 = (float4*)smem;
    const float4* gf4 = (const float4*)feats;
    // T in named scalars (25 regs)
    const float T00=trans[0],  T01=trans[1],  T02=trans[2],  T03=trans[3],  T04=trans[4];
    const float T10=trans[5],  T11=trans[6],  T12=trans[7],  T13=trans[8],  T14=trans[9];
    const float T20=trans[10], T21=trans[11], T22=trans[12], T23=trans[13], T24=trans[14];
    const float T30=trans[15], T31=trans[16], T32=trans[17], T33=trans[18], T34=trans[19];
    const float T40=trans[20], T41=trans[21], T42=trans[22], T43=trans[23], T44=trans[24];
    float fv0 = NEGV, fv1 = NEGV, fv2 = NEGV, fv3 = 0.f, fv4 = NEGV; // START=3

#define VROW(Ta,Tb,Tc,Td,Te, OUTM, OUTI)                                   \
    {                                                                       \
      const float n0 = fv0 + Ta, n1 = fv1 + Tb, n2 = fv2 + Tc,              \
                  n3 = fv3 + Td, n4 = fv4 + Te;                             \
      OUTM = fmaxf(fmaxf(fmaxf(n0, n1), fmaxf(n2, n3)), n4);                \
      OUTI = (n0 == OUTM) ? 0 : ((n1 == OUTM) ? 1 : ((n2 == OUTM) ? 2 :     \
             ((n3 == OUTM) ? 3 : 4)));                                      \
    }
#define VSTEP(fa, fe, tcur)                                                 \
    {                                                                       \
      float m0,m1,m2,m3,m4; int i0,i1,i2,i3,i4;                             \
      VROW(T00,T01,T02,T03,T04, m0,i0)                                      \
      VROW(T10,T11,T12,T13,T14, m1,i1)                                      \
      VROW(T20,T21,T22,T23,T24, m2,i2)                                      \
      VROW(T30,T31,T32,T33,T34, m3,i3)                                      \
      VROW(T40,T41,T42,T43,T44, m4,i4)                                      \
      const int pack = i0 | (i1<<4) | (i2<<8) | (i3<<12) | (i4<<16);        \
      fv0 = m0 + (fa).x; fv1 = m1 + (fa).y; fv2 = m2 + (fa).z;              \
      fv3 = m3 + (fa).w; fv4 = m4 + (fe);                                   \
      if (lane == 0) bpw[tcur] = pack;                                      \
    }

    for (int c = 0; c < TSEQ/512; c++){
      // stage 512 steps (1024 float4) coalesced: lane does 16 float4
      #pragma unroll
      for (int i = 0; i < 16; i++)
        sf4[i*64 + lane] = gf4[(size_t)c*1024 + i*64 + lane];
      asm volatile("s_waitcnt vmcnt(0) lgkmcnt(0)" ::: "memory");
      for (int tt = 0; tt < 512; tt += 4){
        const float4 a0 = sf4[(tt+0)*2];
        const float  e0 = sf[(tt+0)*8 + 4];
        const float4 a1 = sf4[(tt+1)*2];
        const float  e1 = sf[(tt+1)*8 + 4];
        const float4 a2 = sf4[(tt+2)*2];
        const float  e2 = sf[(tt+2)*8 + 4];
        const float4 a3 = sf4[(tt+3)*2];
        const float  e3 = sf[(tt+3)*8 + 4];
        const int tc = c*512 + tt;
        VSTEP(a0, e0, tc+0)
        VSTEP(a1, e1, tc+1)
        VSTEP(a2, e2, tc+2)
        VSTEP(a3, e3, tc+3)
      }
    }
    {
      const float n0 = fv0 + T40, n1 = fv1 + T41, n2 = fv2 + T42,
                  n3 = fv3 + T43, n4 = fv4 + T44;   // STOP row
      const float m  = fmaxf(fmaxf(fmaxf(n0, n1), fmaxf(n2, n3)), n4);
      const int btag = (n0 == m) ? 0 : ((n1 == m) ? 1 : ((n2 == m) ? 2 : ((n3 == m) ? 3 : 4)));
      if (lane == 0){ out[0] = m; out[TSEQ] = (float)btag; }
      int tag = btag;
      for (int tb = TSEQ - 1; tb >= 1; tb -= 16){
        int w[16];
        #pragma unroll
        for (int i = 0; i < 16; i++){
          const int t = tb - i;
          w[i] = (t >= 1) ? bpw[t] : 0;
        }
        #pragma unroll
        for (int i = 0; i < 16; i++){
          const int t = tb - i;
          if (t >= 1){
            const int prev = (w[i] >> (tag*4)) & 15;
            if (lane == 0) out[t] = (float)prev;
            tag = prev;
          }
        }
      }
    }
    return;
  }

  if (blockIdx.x >= LSTM_WGS){
    // ================= inproj GEMM role =================
    float (*As)[132] = (float(*)[132])smem;              // 16 x 132
    float (*Bs)[132] = (float(*)[132])(smem + 8448);     // 16 x 132
    int* srow        = (int*)(smem + 16896);             // 128
    const int p   = blockIdx.x - LSTM_WGS;               // 0..1023
    const int ti  = p >> 5;                              // 0..31
    const int yy  = p & 31;                              // 0..31
    const int dir = yy >> 4;
    const int t_tile = dir ? (31 - ti) : ti;             // two-ended production
    const int t0  = t_tile * 128;
    const int n0  = (yy & 15) * 128;
    const float* __restrict__ W    = dir ? Wib : Wif;
    const float* __restrict__ bias = dir ? bb : bf;
    if (tid < 128) srow[tid] = sent[t0 + tid];
    __syncthreads();
    const int lr = tid >> 2;            // 0..127
    const int kq = (tid & 3) * 4;
    const float* ea = emb + (size_t)srow[lr]   * EMBD + kq;
    const float* wb = W + (size_t)(n0 + lr)    * EMBD + kq;
    const int tx = tid & 15, ty = tid >> 4;   // ty 0..31
    float acc[4][8];
    #pragma unroll
    for (int i = 0; i < 4; i++)
      #pragma unroll
      for (int j = 0; j < 8; j++) acc[i][j] = 0.f;

    for (int k0 = 0; k0 < EMBD; k0 += 16){
      float4 va = *(const float4*)(ea + k0);
      float4 vb = *(const float4*)(wb + k0);
      As[kq+0][lr] = va.x; As[kq+1][lr] = va.y; As[kq+2][lr] = va.z; As[kq+3][lr] = va.w;
      Bs[kq+0][lr] = vb.x; Bs[kq+1][lr] = vb.y; Bs[kq+2][lr] = vb.z; Bs[kq+3][lr] = vb.w;
      __syncthreads();
      #pragma unroll
      for (int k = 0; k < 16; k++){
        float a[4], b[8];
        *(float4*)&a[0] = *(const float4*)&As[k][ty*4];
        #pragma unroll
        for (int j = 0; j < 8; j++) b[j] = Bs[k][tx + 16*j];
        #pragma unroll
        for (int i = 0; i < 4; i++)
          #pragma unroll
          for (int j = 0; j < 8; j++)
            acc[i][j] = fmaf(a[i], b[j], acc[i][j]);
      }
      __syncthreads();
    }
    float bj[8];
    #pragma unroll
    for (int j = 0; j < 8; j++) bj[j] = bias[n0 + tx + 16*j];
    float* Abase = A + (size_t)dir * TSEQ * NGATE;
    #pragma unroll
    for (int i = 0; i < 4; i++){
      float* dst = Abase + (size_t)(t0 + ty*4 + i) * NGATE + n0 + tx;
      #pragma unroll
      for (int j = 0; j < 8; j++) dst[16*j] = acc[i][j] + bj[j];
    }
    __syncthreads();   // drains every wave's stores (HIP barrier semantics)
    if (tid == 0)
      __hip_atomic_fetch_add(&rdy[dir*32 + t_tile], 1,
                             __ATOMIC_RELEASE, __HIP_MEMORY_SCOPE_AGENT);
    return;
  }

  // ================= persistent lstm role =================
  float* hlbuf = (float*)smem;                 // [2][8*68]
  const int bid  = blockIdx.x;
  const int dir  = bid >> 5;
  const int wg   = bid & 31;
  const int lane = tid & 63;
  const int wv   = tid >> 6;        // wave 0..7 = slice index
  const int ul   = tid >> 5;        // unit local 0..15
  const int g    = (tid >> 3) & 3;  // gate i,f,g,o
  const int q    = tid & 7;         // column octant
  const int unit = wg*16 + ul;
  const float* __restrict__ Wh = dir ? Whb : Whf;

  float wreg[64];                   // Wh[g*512+unit][q*64 .. q*64+63]
  {
    const float* wr = Wh + (size_t)(g*HH + unit)*HH + q*64;
    #pragma unroll
    for (int j4 = 0; j4 < 16; j4++){
      float4 vv;
      // volatile load: result cannot be rematerialized -> stays in VGPRs
      asm volatile("global_load_dwordx4 %0, %1, off\n\t"
                   "s_waitcnt vmcnt(0)"
                   : "=v"(vv) : "v"(wr + 4*j4) : "memory");
      wreg[4*j4+0]=vv.x; wreg[4*j4+1]=vv.y; wreg[4*j4+2]=vv.z; wreg[4*j4+3]=vv.w;
    }
  }
  float creg = 0.f;
  if (g == 0 && q == 0) creg = c0[dir*HH + unit];

  u64* mb = hx2 + (size_t)dir*2*HH;
  const float* __restrict__ Ab = A + (size_t)dir*TSEQ*NGATE;
  const int sidx = (wv << 6) + lane;            // this wave's pair index

  // tile-gate + A prefetch for s=0
  int cur_tile = (dir ? (TSEQ - 1) : 0) >> 7;
  {
    const int* rf = rdy + dir*32 + cur_tile;
    while (__hip_atomic_load(rf, __ATOMIC_ACQUIRE, __HIP_MEMORY_SCOPE_AGENT) < 16)
      __builtin_amdgcn_s_sleep(2);
  }
  float av = 0.f;
  if (q == 0) av = Ab[(size_t)(dir ? (TSEQ - 1) : 0)*NGATE + g*HH + unit];

  for (int s = 0; s < TSEQ; s++){
    const int t = dir ? (TSEQ - 1 - s) : s;

    {  // every wave: poll own 64-pair slice (1 load/lane/round, masked reload)
      u64* src = mb + (size_t)(s & 1)*HH;
      const u32 su = (u32)s;
      u64 v = __hip_atomic_load(&src[sidx], __ATOMIC_RELAXED, __HIP_MEMORY_SCOPE_AGENT);
      while (!__all((u32)(v >> 32) == su)){
        if ((u32)(v >> 32) != su)
          v = __hip_atomic_load(&src[sidx], __ATOMIC_RELAXED, __HIP_MEMORY_SCOPE_AGENT);
      }
      hlbuf[(s & 1)*(8*68) + wv*68 + lane] = __uint_as_float((u32)v);
    }
    __syncthreads();

    // prefetch A for step s+1 (resolves under the matvec, off the poll path)
    float av_next = 0.f;
    if (s + 1 < TSEQ){
      const int t1 = dir ? (TSEQ - 2 - s) : (s + 1);
      const int tile1 = t1 >> 7;
      if (tile1 != cur_tile){
        cur_tile = tile1;
        const int* rf = rdy + dir*32 + tile1;
        while (__hip_atomic_load(rf, __ATOMIC_ACQUIRE, __HIP_MEMORY_SCOPE_AGENT) < 16)
          __builtin_amdgcn_s_sleep(2);
      }
      if (q == 0) av_next = Ab[(size_t)t1*NGATE + g*HH + unit];
    }

    // matvec: 64 FMAs from LDS chunk q (weights register-resident)
    const float* hq = hlbuf + (s & 1)*(8*68) + q*68;
    float p0 = 0.f, p1 = 0.f, p2 = 0.f, p3 = 0.f;
    #pragma unroll
    for (int j4 = 0; j4 < 16; j4++){
      float4 h4 = *(const float4*)(hq + 4*j4);
      p0 = fmaf(wreg[4*j4+0], h4.x, p0);
      p1 = fmaf(wreg[4*j4+1], h4.y, p1);
      p2 = fmaf(wreg[4*j4+2], h4.z, p2);
      p3 = fmaf(wreg[4*j4+3], h4.w, p3);
    }
    float acc = ((p0 + p1) + (p2 + p3)) + av;
    acc += __shfl_xor(acc, 1);
    acc += __shfl_xor(acc, 2);
    acc += __shfl_xor(acc, 4);
    // parallel nonlinearity: one transcendental per gate lane
    const float act = (g == 2) ? tanhf(acc) : sigm(acc);
    const float f_ = __shfl_down(act, 8);
    const float g_ = __shfl_down(act, 16);
    const float o_ = __shfl_down(act, 24);
    if (g == 0 && q == 0){
      const float c2 = f_*creg + act*g_;
      const float h2 = o_*tanhf(c2);
      creg = c2;
      // publish FIRST (critical path), bookkeeping store after
      __hip_atomic_store(&mb[(size_t)((s + 1) & 1)*HH + unit], pack_pair(h2, (u32)(s + 1)),
                         __ATOMIC_RELAXED, __HIP_MEMORY_SCOPE_AGENT);
      hseq[((size_t)dir*TSEQ + t)*HH + unit] = h2;
    }
    av = av_next;
  }

  // ---------- feats epilogue: wait for all 64 lstm blocks, then 64 t-rows ------
  __syncthreads();   // all this block's hseq stores issued
  if (tid == 0)
    __hip_atomic_fetch_add(&rdy[65], 1, __ATOMIC_RELEASE, __HIP_MEMORY_SCOPE_AGENT);
  while (__hip_atomic_load(&rdy[65], __ATOMIC_ACQUIRE, __HIP_MEMORY_SCOPE_AGENT) < LSTM_WGS)
    __builtin_amdgcn_s_sleep(2);
  {
    const int wvi = tid >> 6;    // wave 0..7, each does 8 t values
    #pragma unroll
    for (int k = 0; k < 8; k++){
      const int t = bid*64 + wvi*8 + k;
      const float* hf = hseq + (size_t)t*HH;
      const float* hb = hseq + (size_t)(TSEQ + t)*HH;
      float x[16];
      #pragma unroll
      for (int j = 0; j < 8; j++) x[j]     = hf[lane + 64*j];
      #pragma unroll
      for (int j = 0; j < 8; j++) x[8 + j] = hb[lane + 64*j];
      #pragma unroll
      for (int n = 0; n < NTAGS; n++){
        const float* wr = Wout + (size_t)n*(2*HH);
        float p = 0.f;
        #pragma unroll
        for (int j = 0; j < 8; j++) p = fmaf(x[j],     wr[lane + 64*j],      p);
        #pragma unroll
        for (int j = 0; j < 8; j++) p = fmaf(x[8 + j], wr[HH + lane + 64*j], p);
        #pragma unroll
        for (int d = 1; d < 64; d <<= 1) p += __shfl_xor(p, d);
        if (lane == 0) feats[t*8 + n] = p + bout[n];
      }
    }
  }
  __syncthreads();   // all this block's feats stores issued
  if (tid == 0)
    __hip_atomic_fetch_add(&rdy[66], 1, __ATOMIC_RELEASE, __HIP_MEMORY_SCOPE_AGENT);
}

extern "C" void kernel_launch(void* const* d_in, const int* in_sizes, int n_in,
                              void* d_out, int out_size, void* d_ws, size_t ws_size,
                              hipStream_t stream) {
  const int*   sent = (const int*)  d_in[0];
  const float* emb  = (const float*)d_in[1];
  const float* Wihf = (const float*)d_in[2];
  const float* Whhf = (const float*)d_in[3];
  const float* bf_  = (const float*)d_in[4];
  const float* Wihb = (const float*)d_in[5];
  const float* Whhb = (const float*)d_in[6];
  const float* bb_  = (const float*)d_in[7];
  const float* Wout = (const float*)d_in[8];
  const float* bout = (const float*)d_in[9];
  const float* trans= (const float*)d_in[10];
  const float* h0   = (const float*)d_in[11];
  const float* c0   = (const float*)d_in[12];
  float* out = (float*)d_out;

  float* ws   = (float*)d_ws;
  float* A    = ws;                                  // [2][T][2048]
  float* hseq = A    + (size_t)2*TSEQ*NGATE;         // [2][T][512]
  u64*   hx2  = (u64*)(hseq + (size_t)2*TSEQ*HH);    // [2][2][512] (tag,val) pairs
  float* fe   = (float*)(hx2 + 2048);                // [T][8]
  int*   bpw  = (int*)(fe + (size_t)TSEQ*8);         // [T] packed nibbles
  int*   rdy  = bpw + TSEQ;                          // [64] tile-ready + [65][66]
  (void)ws_size;

  k_init<<<1, 1024, 0, stream>>>(h0, hx2, rdy);
  k_fused<<<VIT_BLOCK + 1, 512, 0, stream>>>(
      sent, emb, Wihf, bf_, Wihb, bb_, Whhf, Whhb, c0, Wout, bout, trans,
      A, hseq, fe, bpw, out, hx2, rdy);
}

// Round 17
// 7672.037 us; speedup vs baseline: 1.1290x; 1.0924x over previous
//
#include <hip/hip_runtime.h>
#include <hip/hip_bf16.h>
#include <math.h>

#define TSEQ 4096
#define EMBD 1024
#define HH   512
#define NTAGS 5
#define NGATE 2048
#define NEGV (-10000.0f)
#define START_TAG 3
#define STOP_TAG 4
#define LSTM_WGS 64
#define PROJ_WGS 1024
#define VIT_BLOCK (LSTM_WGS + PROJ_WGS)

typedef unsigned long long u64;
typedef unsigned int u32;

__device__ __forceinline__ float sigm(float x){ return 1.0f/(1.0f+expf(-x)); }

__device__ __forceinline__ u64 pack_pair(float h, u32 tag){
  return ((u64)tag << 32) | (u64)__float_as_uint(h);
}
__device__ __forceinline__ float rdlane_f(float v, int l){
  return __uint_as_float((u32)__builtin_amdgcn_readlane(__float_as_uint(v), l));
}

// ---------------- init: prime h pair buffers + zero control counters ----------
__global__ void k_init(const float* __restrict__ h0, u64* __restrict__ hx2,
                       int* __restrict__ rdy){
  int tid = threadIdx.x;
  if (tid < 1024){
    int dir = tid >> 9, u = tid & 511;
    hx2[(dir*2 + 0)*HH + u] = pack_pair(h0[dir*HH + u], 0u);
    hx2[(dir*2 + 1)*HH + u] = pack_pair(0.f, 0xFFFFFFFFu);
  }
  if (tid < 96) rdy[tid] = 0;  // [0..63] tile-ready, [65] lstm-done, [66] feats-done
}

// ------- fully fused: BiLSTM + inproj GEMM + feats epilogue + viterbi ----------
// blocks 0..63: lstm (+feats epilogue). 64..1087: inproj GEMM. 1088: viterbi.
// R17: viterbi is VALU-ISSUE-bound on its single wave (~85 uniform VALU/step;
// R14-R16's memory theories all falsified by identical 1.5ms across spilled/
// named-reg/LDS-staged variants). Lane-parallel rows: lane r computes trellis
// row r only (~16 VALU), redistribution via readlane (exec-independent).
// Per-row arithmetic is op-for-op identical -> bit-identical path.
__global__ __launch_bounds__(512, 2) void k_fused(
    const int* __restrict__ sent, const float* __restrict__ emb,
    const float* __restrict__ Wif, const float* __restrict__ bf,
    const float* __restrict__ Wib, const float* __restrict__ bb,
    const float* __restrict__ Whf, const float* __restrict__ Whb,
    const float* __restrict__ c0, const float* __restrict__ Wout,
    const float* __restrict__ bout, const float* __restrict__ trans,
    float* __restrict__ A, float* __restrict__ hseq, float* __restrict__ feats,
    int* __restrict__ bpw, float* __restrict__ out,
    u64* __restrict__ hx2, int* __restrict__ rdy){
  __shared__ __align__(16) char smem[17408];
  const int tid = threadIdx.x;

  if (blockIdx.x == VIT_BLOCK){
    // ================= viterbi role (1 wave, lane-parallel rows) =============
    if (tid >= 64) return;
    const int lane = tid;
    while (__hip_atomic_load(&rdy[66], __ATOMIC_ACQUIRE, __HIP_MEMORY_SCOPE_AGENT) < LSTM_WGS)
      __builtin_amdgcn_s_sleep(8);
    float*  sf  = (float*)smem;        // staged feats chunk: 512 steps x 8 = 16KB
    float4* sf4 = (float4*)smem;
    const float4* gf4 = (const float4*)feats;
    const int rr = (lane < 5) ? lane : 0;     // my trellis row
    // lane r holds row r of T: n_f = fv_f + Tr[f]
    const float Tr0 = trans[rr*NTAGS+0], Tr1 = trans[rr*NTAGS+1],
                Tr2 = trans[rr*NTAGS+2], Tr3 = trans[rr*NTAGS+3],
                Tr4 = trans[rr*NTAGS+4];
    // STOP row (uniform, terminal step)
    const float S0=trans[STOP_TAG*NTAGS+0], S1=trans[STOP_TAG*NTAGS+1],
                S2=trans[STOP_TAG*NTAGS+2], S3=trans[STOP_TAG*NTAGS+3],
                S4=trans[STOP_TAG*NTAGS+4];
    float fv0 = NEGV, fv1 = NEGV, fv2 = NEGV, fv3 = 0.f, fv4 = NEGV; // START=3

    for (int c = 0; c < TSEQ/512; c++){
      // stage 512 steps (1024 float4) coalesced: lane does 16 float4
      #pragma unroll
      for (int i = 0; i < 16; i++)
        sf4[i*64 + lane] = gf4[(size_t)c*1024 + i*64 + lane];
      asm volatile("s_waitcnt vmcnt(0) lgkmcnt(0)" ::: "memory");
      for (int tt = 0; tt < 512; tt++){
        const float featr = sf[tt*8 + rr];            // lane r: feats[t][r]
        // row r: identical add order / max tree / first-match cascade
        const float n0 = fv0 + Tr0, n1 = fv1 + Tr1, n2 = fv2 + Tr2,
                    n3 = fv3 + Tr3, n4 = fv4 + Tr4;
        const float m  = fmaxf(fmaxf(fmaxf(n0, n1), fmaxf(n2, n3)), n4);
        const int idx  = (n0 == m) ? 0 : ((n1 == m) ? 1 : ((n2 == m) ? 2 :
                         ((n3 == m) ? 3 : 4)));
        const float nf = m + featr;
        // redistribute new fv (uniform via readlane) + build pack in SALU
        fv0 = rdlane_f(nf, 0); fv1 = rdlane_f(nf, 1); fv2 = rdlane_f(nf, 2);
        fv3 = rdlane_f(nf, 3); fv4 = rdlane_f(nf, 4);
        const int i0 = __builtin_amdgcn_readlane(idx, 0);
        const int i1 = __builtin_amdgcn_readlane(idx, 1);
        const int i2 = __builtin_amdgcn_readlane(idx, 2);
        const int i3 = __builtin_amdgcn_readlane(idx, 3);
        const int i4 = __builtin_amdgcn_readlane(idx, 4);
        const int pack = i0 | (i1<<4) | (i2<<8) | (i3<<12) | (i4<<16);
        if (lane == 0) bpw[c*512 + tt] = pack;
      }
    }
    {
      const float n0 = fv0 + S0, n1 = fv1 + S1, n2 = fv2 + S2,
                  n3 = fv3 + S3, n4 = fv4 + S4;
      const float m  = fmaxf(fmaxf(fmaxf(n0, n1), fmaxf(n2, n3)), n4);
      const int btag = (n0 == m) ? 0 : ((n1 == m) ? 1 : ((n2 == m) ? 2 : ((n3 == m) ? 3 : 4)));
      if (lane == 0){ out[0] = m; out[TSEQ] = (float)btag; }
      int tag = btag;
      for (int tb = TSEQ - 1; tb >= 1; tb -= 16){
        int w[16];
        #pragma unroll
        for (int i = 0; i < 16; i++){
          const int t = tb - i;
          w[i] = (t >= 1) ? bpw[t] : 0;
        }
        #pragma unroll
        for (int i = 0; i < 16; i++){
          const int t = tb - i;
          if (t >= 1){
            const int prev = (w[i] >> (tag*4)) & 15;
            if (lane == 0) out[t] = (float)prev;
            tag = prev;
          }
        }
      }
    }
    return;
  }

  if (blockIdx.x >= LSTM_WGS){
    // ================= inproj GEMM role =================
    float (*As)[132] = (float(*)[132])smem;              // 16 x 132
    float (*Bs)[132] = (float(*)[132])(smem + 8448);     // 16 x 132
    int* srow        = (int*)(smem + 16896);             // 128
    const int p   = blockIdx.x - LSTM_WGS;               // 0..1023
    const int ti  = p >> 5;                              // 0..31
    const int yy  = p & 31;                              // 0..31
    const int dir = yy >> 4;
    const int t_tile = dir ? (31 - ti) : ti;             // two-ended production
    const int t0  = t_tile * 128;
    const int n0  = (yy & 15) * 128;
    const float* __restrict__ W    = dir ? Wib : Wif;
    const float* __restrict__ bias = dir ? bb : bf;
    if (tid < 128) srow[tid] = sent[t0 + tid];
    __syncthreads();
    const int lr = tid >> 2;            // 0..127
    const int kq = (tid & 3) * 4;
    const float* ea = emb + (size_t)srow[lr]   * EMBD + kq;
    const float* wb = W + (size_t)(n0 + lr)    * EMBD + kq;
    const int tx = tid & 15, ty = tid >> 4;   // ty 0..31
    float acc[4][8];
    #pragma unroll
    for (int i = 0; i < 4; i++)
      #pragma unroll
      for (int j = 0; j < 8; j++) acc[i][j] = 0.f;

    for (int k0 = 0; k0 < EMBD; k0 += 16){
      float4 va = *(const float4*)(ea + k0);
      float4 vb = *(const float4*)(wb + k0);
      As[kq+0][lr] = va.x; As[kq+1][lr] = va.y; As[kq+2][lr] = va.z; As[kq+3][lr] = va.w;
      Bs[kq+0][lr] = vb.x; Bs[kq+1][lr] = vb.y; Bs[kq+2][lr] = vb.z; Bs[kq+3][lr] = vb.w;
      __syncthreads();
      #pragma unroll
      for (int k = 0; k < 16; k++){
        float a[4], b[8];
        *(float4*)&a[0] = *(const float4*)&As[k][ty*4];
        #pragma unroll
        for (int j = 0; j < 8; j++) b[j] = Bs[k][tx + 16*j];
        #pragma unroll
        for (int i = 0; i < 4; i++)
          #pragma unroll
          for (int j = 0; j < 8; j++)
            acc[i][j] = fmaf(a[i], b[j], acc[i][j]);
      }
      __syncthreads();
    }
    float bj[8];
    #pragma unroll
    for (int j = 0; j < 8; j++) bj[j] = bias[n0 + tx + 16*j];
    float* Abase = A + (size_t)dir * TSEQ * NGATE;
    #pragma unroll
    for (int i = 0; i < 4; i++){
      float* dst = Abase + (size_t)(t0 + ty*4 + i) * NGATE + n0 + tx;
      #pragma unroll
      for (int j = 0; j < 8; j++) dst[16*j] = acc[i][j] + bj[j];
    }
    __syncthreads();   // drains every wave's stores (HIP barrier semantics)
    if (tid == 0)
      __hip_atomic_fetch_add(&rdy[dir*32 + t_tile], 1,
                             __ATOMIC_RELEASE, __HIP_MEMORY_SCOPE_AGENT);
    return;
  }

  // ================= persistent lstm role =================
  float* hlbuf = (float*)smem;                 // [2][8*68]
  const int bid  = blockIdx.x;
  const int dir  = bid >> 5;
  const int wg   = bid & 31;
  const int lane = tid & 63;
  const int wv   = tid >> 6;        // wave 0..7 = slice index
  const int ul   = tid >> 5;        // unit local 0..15
  const int g    = (tid >> 3) & 3;  // gate i,f,g,o
  const int q    = tid & 7;         // column octant
  const int unit = wg*16 + ul;
  const float* __restrict__ Wh = dir ? Whb : Whf;

  float wreg[64];                   // Wh[g*512+unit][q*64 .. q*64+63]
  {
    const float* wr = Wh + (size_t)(g*HH + unit)*HH + q*64;
    #pragma unroll
    for (int j4 = 0; j4 < 16; j4++){
      float4 vv;
      // volatile load: result cannot be rematerialized -> stays in VGPRs
      asm volatile("global_load_dwordx4 %0, %1, off\n\t"
                   "s_waitcnt vmcnt(0)"
                   : "=v"(vv) : "v"(wr + 4*j4) : "memory");
      wreg[4*j4+0]=vv.x; wreg[4*j4+1]=vv.y; wreg[4*j4+2]=vv.z; wreg[4*j4+3]=vv.w;
    }
  }
  float creg = 0.f;
  if (g == 0 && q == 0) creg = c0[dir*HH + unit];

  u64* mb = hx2 + (size_t)dir*2*HH;
  const float* __restrict__ Ab = A + (size_t)dir*TSEQ*NGATE;
  const int sidx = (wv << 6) + lane;            // this wave's pair index

  // tile-gate + A prefetch for s=0
  int cur_tile = (dir ? (TSEQ - 1) : 0) >> 7;
  {
    const int* rf = rdy + dir*32 + cur_tile;
    while (__hip_atomic_load(rf, __ATOMIC_ACQUIRE, __HIP_MEMORY_SCOPE_AGENT) < 16)
      __builtin_amdgcn_s_sleep(2);
  }
  float av = 0.f;
  if (q == 0) av = Ab[(size_t)(dir ? (TSEQ - 1) : 0)*NGATE + g*HH + unit];

  for (int s = 0; s < TSEQ; s++){
    const int t = dir ? (TSEQ - 1 - s) : s;

    {  // every wave: poll own 64-pair slice (1 load/lane/round, masked reload)
      u64* src = mb + (size_t)(s & 1)*HH;
      const u32 su = (u32)s;
      u64 v = __hip_atomic_load(&src[sidx], __ATOMIC_RELAXED, __HIP_MEMORY_SCOPE_AGENT);
      while (!__all((u32)(v >> 32) == su)){
        if ((u32)(v >> 32) != su)
          v = __hip_atomic_load(&src[sidx], __ATOMIC_RELAXED, __HIP_MEMORY_SCOPE_AGENT);
      }
      hlbuf[(s & 1)*(8*68) + wv*68 + lane] = __uint_as_float((u32)v);
    }
    __syncthreads();

    // prefetch A for step s+1 (resolves under the matvec, off the poll path)
    float av_next = 0.f;
    if (s + 1 < TSEQ){
      const int t1 = dir ? (TSEQ - 2 - s) : (s + 1);
      const int tile1 = t1 >> 7;
      if (tile1 != cur_tile){
        cur_tile = tile1;
        const int* rf = rdy + dir*32 + tile1;
        while (__hip_atomic_load(rf, __ATOMIC_ACQUIRE, __HIP_MEMORY_SCOPE_AGENT) < 16)
          __builtin_amdgcn_s_sleep(2);
      }
      if (q == 0) av_next = Ab[(size_t)t1*NGATE + g*HH + unit];
    }

    // matvec: 64 FMAs from LDS chunk q (weights register-resident)
    const float* hq = hlbuf + (s & 1)*(8*68) + q*68;
    float p0 = 0.f, p1 = 0.f, p2 = 0.f, p3 = 0.f;
    #pragma unroll
    for (int j4 = 0; j4 < 16; j4++){
      float4 h4 = *(const float4*)(hq + 4*j4);
      p0 = fmaf(wreg[4*j4+0], h4.x, p0);
      p1 = fmaf(wreg[4*j4+1], h4.y, p1);
      p2 = fmaf(wreg[4*j4+2], h4.z, p2);
      p3 = fmaf(wreg[4*j4+3], h4.w, p3);
    }
    float acc = ((p0 + p1) + (p2 + p3)) + av;
    acc += __shfl_xor(acc, 1);
    acc += __shfl_xor(acc, 2);
    acc += __shfl_xor(acc, 4);
    // parallel nonlinearity: one transcendental per gate lane
    const float act = (g == 2) ? tanhf(acc) : sigm(acc);
    const float f_ = __shfl_down(act, 8);
    const float g_ = __shfl_down(act, 16);
    const float o_ = __shfl_down(act, 24);
    if (g == 0 && q == 0){
      const float c2 = f_*creg + act*g_;
      const float h2 = o_*tanhf(c2);
      creg = c2;
      // publish FIRST (critical path), bookkeeping store after
      __hip_atomic_store(&mb[(size_t)((s + 1) & 1)*HH + unit], pack_pair(h2, (u32)(s + 1)),
                         __ATOMIC_RELAXED, __HIP_MEMORY_SCOPE_AGENT);
      hseq[((size_t)dir*TSEQ + t)*HH + unit] = h2;
    }
    av = av_next;
  }

  // ---------- feats epilogue: wait for all 64 lstm blocks, then 64 t-rows ------
  __syncthreads();   // all this block's hseq stores issued
  if (tid == 0)
    __hip_atomic_fetch_add(&rdy[65], 1, __ATOMIC_RELEASE, __HIP_MEMORY_SCOPE_AGENT);
  while (__hip_atomic_load(&rdy[65], __ATOMIC_ACQUIRE, __HIP_MEMORY_SCOPE_AGENT) < LSTM_WGS)
    __builtin_amdgcn_s_sleep(2);
  {
    const int wvi = tid >> 6;    // wave 0..7, each does 8 t values
    #pragma unroll
    for (int k = 0; k < 8; k++){
      const int t = bid*64 + wvi*8 + k;
      const float* hf = hseq + (size_t)t*HH;
      const float* hb = hseq + (size_t)(TSEQ + t)*HH;
      float x[16];
      #pragma unroll
      for (int j = 0; j < 8; j++) x[j]     = hf[lane + 64*j];
      #pragma unroll
      for (int j = 0; j < 8; j++) x[8 + j] = hb[lane + 64*j];
      #pragma unroll
      for (int n = 0; n < NTAGS; n++){
        const float* wr = Wout + (size_t)n*(2*HH);
        float p = 0.f;
        #pragma unroll
        for (int j = 0; j < 8; j++) p = fmaf(x[j],     wr[lane + 64*j],      p);
        #pragma unroll
        for (int j = 0; j < 8; j++) p = fmaf(x[8 + j], wr[HH + lane + 64*j], p);
        #pragma unroll
        for (int d = 1; d < 64; d <<= 1) p += __shfl_xor(p, d);
        if (lane == 0) feats[t*8 + n] = p + bout[n];
      }
    }
  }
  __syncthreads();   // all this block's feats stores issued
  if (tid == 0)
    __hip_atomic_fetch_add(&rdy[66], 1, __ATOMIC_RELEASE, __HIP_MEMORY_SCOPE_AGENT);
}

extern "C" void kernel_launch(void* const* d_in, const int* in_sizes, int n_in,
                              void* d_out, int out_size, void* d_ws, size_t ws_size,
                              hipStream_t stream) {
  const int*   sent = (const int*)  d_in[0];
  const float* emb  = (const float*)d_in[1];
  const float* Wihf = (const float*)d_in[2];
  const float* Whhf = (const float*)d_in[3];
  const float* bf_  = (const float*)d_in[4];
  const float* Wihb = (const float*)d_in[5];
  const float* Whhb = (const float*)d_in[6];
  const float* bb_  = (const float*)d_in[7];
  const float* Wout = (const float*)d_in[8];
  const float* bout = (const float*)d_in[9];
  const float* trans= (const float*)d_in[10];
  const float* h0   = (const float*)d_in[11];
  const float* c0   = (const float*)d_in[12];
  float* out = (float*)d_out;

  float* ws   = (float*)d_ws;
  float* A    = ws;                                  // [2][T][2048]
  float* hseq = A    + (size_t)2*TSEQ*NGATE;         // [2][T][512]
  u64*   hx2  = (u64*)(hseq + (size_t)2*TSEQ*HH);    // [2][2][512] (tag,val) pairs
  float* fe   = (float*)(hx2 + 2048);                // [T][8]
  int*   bpw  = (int*)(fe + (size_t)TSEQ*8);         // [T] packed nibbles
  int*   rdy  = bpw + TSEQ;                          // [64] tile-ready + [65][66]
  (void)ws_size;

  k_init<<<1, 1024, 0, stream>>>(h0, hx2, rdy);
  k_fused<<<VIT_BLOCK + 1, 512, 0, stream>>>(
      sent, emb, Wihf, bf_, Wihb, bb_, Whhf, Whhb, c0, Wout, bout, trans,
      A, hseq, fe, bpw, out, hx2, rdy);
}